// Round 23
// baseline (115.941 us; speedup 1.0000x reference)
//
#include <hip/hip_runtime.h>
#include <cstdint>

#define NFEAT 4096
#define NHALF 2048
#define DDIM  512
#define QROWS 32768

typedef unsigned short u16;
typedef unsigned char  u8;
typedef unsigned int   u32;
typedef unsigned long long u64;

typedef float  f32x16_t __attribute__((ext_vector_type(16)));
typedef int    i32x4_t  __attribute__((ext_vector_type(4)));
typedef int    i32x8_t  __attribute__((ext_vector_type(8)));

typedef const __attribute__((address_space(1))) void* gas_ptr;
typedef __attribute__((address_space(3))) void* las_ptr;

// monotonic unsigned encoding of float (no NaN/Inf expected)
__device__ __forceinline__ u32 fkey(float f) {
  u32 u = __float_as_uint(f);
  return (u & 0x80000000u) ? ~u : (u | 0x80000000u);
}

// ---------------- kernel 1: l2-normalize rows -> TILED fp8(e4m3) --------------
// fp8 buffers stored PRE-TILED in the GEMM's fragment order: addr(row,k) =
// (row>>5)*16384 + (k>>6)*2048 + ((k>>5)&1)*1024 + ((k>>4)&1)*512 +
// (row&31)*16 + (k&15).  (verified R11/R12, absmax 0.0)
__global__ void k_norm(const float* __restrict__ zi, const float* __restrict__ zj,
                       const float* __restrict__ queue,
                       u8* __restrict__ feat8T, u8* __restrict__ queue8T) {
  int gw = (int)((blockIdx.x * blockDim.x + threadIdx.x) >> 6);
  int lane = threadIdx.x & 63;
  const float* src; u8* dstT; int r31;
  if (gw < NFEAT) {
    src = (gw < NHALF) ? (zi + (size_t)gw * DDIM) : (zj + (size_t)(gw - NHALF) * DDIM);
    dstT = feat8T + (size_t)(gw >> 5) * 16384; r31 = gw & 31;
  } else {
    int r = gw - NFEAT;
    src = queue + (size_t)r * DDIM;
    dstT = queue8T + (size_t)(r >> 5) * 16384; r31 = r & 31;
  }
  float4 v0 = reinterpret_cast<const float4*>(src)[lane * 2];
  float4 v1 = reinterpret_cast<const float4*>(src)[lane * 2 + 1];
  float ss = v0.x*v0.x + v0.y*v0.y + v0.z*v0.z + v0.w*v0.w
           + v1.x*v1.x + v1.y*v1.y + v1.z*v1.z + v1.w*v1.w;
  #pragma unroll
  for (int off = 32; off >= 1; off >>= 1) ss += __shfl_xor(ss, off);
  float inv = 1.0f / fmaxf(sqrtf(ss), 1e-12f);
  float n0 = v0.x*inv, n1 = v0.y*inv, n2 = v0.z*inv, n3 = v0.w*inv;
  float n4 = v1.x*inv, n5 = v1.y*inv, n6 = v1.z*inv, n7 = v1.w*inv;
  u32 p01, p23, p45, p67;
  asm("v_cvt_pk_fp8_f32 %0, %1, %2" : "=v"(p01) : "v"(n0), "v"(n1));
  asm("v_cvt_pk_fp8_f32 %0, %1, %2" : "=v"(p23) : "v"(n2), "v"(n3));
  asm("v_cvt_pk_fp8_f32 %0, %1, %2" : "=v"(p45) : "v"(n4), "v"(n5));
  asm("v_cvt_pk_fp8_f32 %0, %1, %2" : "=v"(p67) : "v"(n6), "v"(n7));
  uint2 w8;
  w8.x = (p01 & 0xFFFFu) | (p23 << 16);
  w8.y = (p45 & 0xFFFFu) | (p67 << 16);
  size_t toff = (size_t)(lane >> 3) * 2048 + ((lane >> 2) & 1) * 1024
              + ((lane >> 1) & 1) * 512 + r31 * 16 + (lane & 1) * 8;
  *reinterpret_cast<uint2*>(dstT + toff) = w8;
}

#define SB0() __builtin_amdgcn_sched_barrier(0)
#define LGKM0_SB() do { asm volatile("s_waitcnt lgkmcnt(0)" ::: "memory"); SB0(); } while (0)
#define VMCNT4() asm volatile("s_waitcnt vmcnt(4)" ::: "memory")
#define VMCNT2() asm volatile("s_waitcnt vmcnt(2)" ::: "memory")
#define VMCNT0() asm volatile("s_waitcnt vmcnt(0)" ::: "memory")
#define SBAR() __builtin_amdgcn_s_barrier()
#define RD(dst, base, off) asm volatile("ds_read_b128 %0, %1 offset:" off \
                                        : "=v"(dst) : "v"(base))
#define MFMA8(ACC, AV, BV) \
  ACC = __builtin_amdgcn_mfma_scale_f32_32x32x64_f8f6f4(AV, BV, ACC, 0, 0, 0, \
        0x7F7F7F7F, 0, 0x7F7F7F7F)

// ---------------- kernel 2: HYBRID fp8 GEMM queue @ feat^T + fused col-argmax -
// R23: wide geometry (block 128Mx256N, 4 waves 2Mx2N, wave 64x128, acc 128)
// with A (queue) in LDS ring-3 (3 x 8KB = 24KB) and B (feat) loaded PER-LANE
// DIRECT from the pre-tiled global buffer into registers (verified R18).
// Per-instance LDS traffic 72KB -> 24KB (A 16KB read + 8KB write); B's 32KB
// rides L2 (~27 B/cyc/CU << 135), latency hidden under the A-FIFO wait via
// compiler-tracked per-register vmcnt. SB0 before each boundary pins load
// hoisting so the manual ledger is sound: within iter t issue stageA(t+2) [2]
// then B(t) [8]; compiler's B(t)-wait before MFMA retires stage(t+1)
// (in-order vmcnt counting, m135); boundary vmcnt(2) (t<=5) leaves only
// stageA(t+2) in flight; t=6 vmcnt(0). WAR: stage into buf (t+2)%3=(t-1)%3
// whose readers lgkm-confirmed before t-1's ending barrier.
// Epilogue = verified R12 in-register col-argmax x 4 n-groups.
__global__ __launch_bounds__(256, 2) void k_argmax_gemm8(
    const u8* __restrict__ feat8T, const u8* __restrict__ queue8T,
    u64* __restrict__ part) {
  __shared__ u8 lds[24576];
  const int tid = threadIdx.x;
  const int w = tid >> 6, lane = tid & 63;
  const int wr = w >> 1, wc = w & 1;
  const int l31 = lane & 31, hi = lane >> 5;
  const int bid = (int)blockIdx.x;
  const int wg = (bid & 7) * 512 + (bid >> 3);   // bijective XCD swizzle (4096 = 8x512)
  const int mt = wg >> 4, ft = wg & 15;          // ft fastest: queue slice L2-resident
  const int brow = mt * 128, bcol = ft * 256;

  // A staging: 8KB/tile = 2 x 16B per thread; dest linear
  const u8* pA = queue8T + (size_t)((brow >> 5) + (tid >> 7)) * 16384 + (tid & 127) * 16;
  const u32 dA = (u32)(size_t)(las_ptr)&lds[tid * 16];

  // A read base (frag m at +0/512 and +2048/2560; buf stride 8192)
  const u32 aAd = (u32)(size_t)(las_ptr)&lds[wr * 4096 + hi * 1024 + l31 * 16];

  // B direct bases: col-blocks ft*8 + wc*4 + n (n = 0..3), per-tile advance 2048
  const int lo = hi * 1024 + l31 * 16;
  const u8* pB0 = feat8T + (size_t)((bcol >> 5) + wc * 4) * 16384 + lo;
  const u8* pB1 = pB0 + 16384;
  const u8* pB2 = pB0 + 32768;
  const u8* pB3 = pB0 + 49152;

  f32x16_t acc00 = {}, acc01 = {}, acc02 = {}, acc03 = {};
  f32x16_t acc10 = {}, acc11 = {}, acc12 = {}, acc13 = {};

  auto stageA = [&](int b, int t) {
    const u32 base = (u32)(b * 8192);
    __builtin_amdgcn_global_load_lds((gas_ptr)(pA + t * 2048),
        (las_ptr)(size_t)(dA + base), 16, 0, 0);
    __builtin_amdgcn_global_load_lds((gas_ptr)(pA + 32768 + t * 2048),
        (las_ptr)(size_t)(dA + base + 4096), 16, 0, 0);
  };

  stageA(0, 0); stageA(1, 1);
  VMCNT2();                 // stage(0) landed; stage(1) in flight
  SBAR();

  #pragma unroll
  for (int t = 0; t < 8; t++) {
    if (t <= 5) stageA((t + 2) % 3, t + 2);
    // B(t): 8 per-lane direct loads (compiler schedules/waits via vmcnt)
    const u8* q0 = pB0 + t * 2048;
    const u8* q1 = pB1 + t * 2048;
    const u8* q2 = pB2 + t * 2048;
    const u8* q3 = pB3 + t * 2048;
    i32x4_t b0l = *reinterpret_cast<const i32x4_t*>(q0);
    i32x4_t b0h = *reinterpret_cast<const i32x4_t*>(q0 + 512);
    i32x4_t b1l = *reinterpret_cast<const i32x4_t*>(q1);
    i32x4_t b1h = *reinterpret_cast<const i32x4_t*>(q1 + 512);
    i32x4_t b2l = *reinterpret_cast<const i32x4_t*>(q2);
    i32x4_t b2h = *reinterpret_cast<const i32x4_t*>(q2 + 512);
    i32x4_t b3l = *reinterpret_cast<const i32x4_t*>(q3);
    i32x4_t b3h = *reinterpret_cast<const i32x4_t*>(q3 + 512);
    // A fragments from LDS buf t%3
    const u32 xa = aAd + (u32)((t % 3) * 8192);
    i32x4_t r0, r1, r2, r3;
    RD(r0, xa, "0");    RD(r1, xa, "512");
    RD(r2, xa, "2048"); RD(r3, xa, "2560");
    LGKM0_SB();
    i32x8_t A0 = __builtin_shufflevector(r0, r1, 0, 1, 2, 3, 4, 5, 6, 7);
    i32x8_t A1 = __builtin_shufflevector(r2, r3, 0, 1, 2, 3, 4, 5, 6, 7);
    i32x8_t B0 = __builtin_shufflevector(b0l, b0h, 0, 1, 2, 3, 4, 5, 6, 7);
    i32x8_t B1 = __builtin_shufflevector(b1l, b1h, 0, 1, 2, 3, 4, 5, 6, 7);
    i32x8_t B2 = __builtin_shufflevector(b2l, b2h, 0, 1, 2, 3, 4, 5, 6, 7);
    i32x8_t B3 = __builtin_shufflevector(b3l, b3h, 0, 1, 2, 3, 4, 5, 6, 7);
    __builtin_amdgcn_s_setprio(1);
    MFMA8(acc00, A0, B0); MFMA8(acc01, A0, B1);
    MFMA8(acc02, A0, B2); MFMA8(acc03, A0, B3);
    MFMA8(acc10, A1, B0); MFMA8(acc11, A1, B1);
    MFMA8(acc12, A1, B2); MFMA8(acc13, A1, B3);
    __builtin_amdgcn_s_setprio(0);
    if (t < 7) {
      SB0();                       // pin loads: nothing crosses the boundary
      if (t <= 5) VMCNT2(); else VMCNT0();
      SBAR();
    }
  }

  // epilogue: per-feature (column = lane pair) argmax over wave's 64 queue rows.
  // C/D 32x32: col = lane&31, row = (reg&3) + 8*(reg>>2) + 4*hi (+m*32).
  const int mslot = mt * 2 + wr;
#define AMAX_N(ACC0, ACC1, NOFF) do { \
    float bv = -3.0e38f; int br = 0; \
    _Pragma("unroll") \
    for (int reg = 0; reg < 16; reg++) { \
      float v = ACC0[reg]; int lr = (reg & 3) + 8 * (reg >> 2); \
      if (v > bv) { bv = v; br = lr; } } \
    _Pragma("unroll") \
    for (int reg = 0; reg < 16; reg++) { \
      float v = ACC1[reg]; int lr = 32 + (reg & 3) + 8 * (reg >> 2); \
      if (v > bv) { bv = v; br = lr; } } \
    u32 q = (u32)(brow + wr * 64 + br + 4 * hi); \
    u64 key = ((u64)fkey(bv) << 32) | (u64)(0xFFFFFFFFu - q); \
    u64 o = __shfl_xor(key, 32); \
    key = key > o ? key : o; \
    int j = bcol + wc * 128 + NOFF + l31; \
    if (hi == 0) part[(size_t)j * 512 + mslot] = key; \
  } while (0)
  AMAX_N(acc00, acc10, 0);
  AMAX_N(acc01, acc11, 32);
  AMAX_N(acc02, acc12, 64);
  AMAX_N(acc03, acc13, 96);
#undef AMAX_N
}

// ---------------- kernel 3: reduce argmax partials + FUSED row gather ---------
__global__ void k_reduce_gather(const u64* __restrict__ part,
                                const u8* __restrict__ queue8T,
                                u8* __restrict__ nn8T) {
  int row = (int)((blockIdx.x * blockDim.x + threadIdx.x) >> 6);
  int lane = threadIdx.x & 63;
  const u64* p = part + (size_t)row * 512;
  u64 best = 0;
  #pragma unroll
  for (int i = 0; i < 8; i++) { u64 v = p[lane * 8 + i]; best = best > v ? best : v; }
  #pragma unroll
  for (int off = 1; off < 64; off <<= 1) { u64 o = __shfl_xor(best, off); best = best > o ? best : o; }
  int g = (int)(0xFFFFFFFFu - (u32)(best & 0xFFFFFFFFu));
  if (lane < 32) {
    const uint4 v = *reinterpret_cast<const uint4*>(
        queue8T + (size_t)(g >> 5) * 16384 + lane * 512 + (g & 31) * 16);
    *reinterpret_cast<uint4*>(
        nn8T + (size_t)(row >> 5) * 16384 + lane * 512 + (row & 31) * 16) = v;
  }
}

// ---------------- R12 tile engine (narrow, verified) for k_sim_gemm8 ----------
#define FP8_TILE(XA, XB) do { \
    i32x4_t a00, a01, a10, a11, b00, b01, b10, b11; \
    RD(a00, XA, "0"); RD(a01, XA, "512"); \
    RD(a10, XA, "2048"); RD(a11, XA, "2560"); \
    RD(b00, XB, "0"); RD(b01, XB, "512"); \
    RD(b10, XB, "2048"); RD(b11, XB, "2560"); \
    LGKM0_SB(); \
    i32x8_t A0 = __builtin_shufflevector(a00, a01, 0, 1, 2, 3, 4, 5, 6, 7); \
    i32x8_t A1 = __builtin_shufflevector(a10, a11, 0, 1, 2, 3, 4, 5, 6, 7); \
    i32x8_t B0 = __builtin_shufflevector(b00, b01, 0, 1, 2, 3, 4, 5, 6, 7); \
    i32x8_t B1 = __builtin_shufflevector(b10, b11, 0, 1, 2, 3, 4, 5, 6, 7); \
    __builtin_amdgcn_s_setprio(1); \
    MFMA8(acc00, A0, B0); \
    MFMA8(acc01, A0, B1); \
    MFMA8(acc10, A1, B0); \
    MFMA8(acc11, A1, B1); \
    __builtin_amdgcn_s_setprio(0); \
  } while (0)

#define FP8_MAIN_LOOP() do { \
  stage(0, 0); stage(1, 1); \
  VMCNT4(); \
  SBAR(); \
  _Pragma("unroll") \
  for (int t = 0; t < 8; t++) { \
    if (t <= 5) stage((t + 2) % 3, t + 2); \
    const u32 bb = (u32)((t % 3) * 16384); \
    FP8_TILE(aAd + bb, bAd + bb); \
    if (t < 7) { \
      if (t <= 5) VMCNT4(); else VMCNT0(); \
      SBAR(); \
    } \
  } } while (0)

// ---------------- kernel 4: fp8 GEMM feat @ nn^T + fused col-lse + positives --
// (verified R16: contiguous nn8T staging, lane-pair lse + hi merge)
__global__ __launch_bounds__(256, 2) void k_sim_gemm8(
    const u8* __restrict__ feat8T, const u8* __restrict__ nn8T,
    float2* __restrict__ lsep, float* __restrict__ pos) {
  __shared__ u8 lds[49152];
  const int tid = threadIdx.x;
  const int w = tid >> 6, lane = tid & 63;
  const int wr = w >> 1, wc = w & 1;
  const int l31 = lane & 31, hi = lane >> 5;
  const int bid = (int)blockIdx.x;
  const int wg = (bid & 7) * 128 + (bid >> 3);   // bijective XCD swizzle (1024 = 8x128)
  const int mt = wg >> 5, nt = wg & 31;
  const int mtb = mt * 128, ntb = nt * 128;

  const u8* pA = feat8T + (size_t)(mtb >> 5) * 16384 + (tid >> 7) * 16384 + (tid & 127) * 16;
  const u8* pB = nn8T   + (size_t)(ntb >> 5) * 16384 + (tid >> 7) * 16384 + (tid & 127) * 16;
  const u32 dA = (u32)(size_t)(las_ptr)&lds[tid * 16];
  const u32 dB = dA + 8192;

  const u32 aAd = (u32)(size_t)(las_ptr)&lds[wr * 4096 + hi * 1024 + l31 * 16];
  const u32 bAd = (u32)(size_t)(las_ptr)&lds[8192 + wc * 4096 + hi * 1024 + l31 * 16];

  f32x16_t acc00 = {}, acc01 = {}, acc10 = {}, acc11 = {};

  auto stage = [&](int b, int t) {
    const u32 base = (u32)(b * 16384);
    __builtin_amdgcn_global_load_lds((gas_ptr)(pA + t * 2048),         (las_ptr)(size_t)(dA + base), 16, 0, 0);
    __builtin_amdgcn_global_load_lds((gas_ptr)(pA + 32768 + t * 2048), (las_ptr)(size_t)(dA + base + 4096), 16, 0, 0);
    __builtin_amdgcn_global_load_lds((gas_ptr)(pB + t * 2048),         (las_ptr)(size_t)(dB + base), 16, 0, 0);
    __builtin_amdgcn_global_load_lds((gas_ptr)(pB + 32768 + t * 2048), (las_ptr)(size_t)(dB + base + 4096), 16, 0, 0);
  };

  FP8_MAIN_LOOP();

  // epilogue: per-column (lane pair = nn row j) lse over 64 feat rows,
  // scale by 1/T=2, diag mask, positive capture, hi-pair online-softmax merge.
  const int mslot = mt * 2 + wr;
  const int ibase = mtb + wr * 64 + 4 * hi;
  #pragma unroll
  for (int n = 0; n < 2; n++) {
    const int j = ntb + wc * 64 + n * 32 + l31;
    const int jp = j ^ NHALF;
    float mx = -3.0e38f;
    #pragma unroll
    for (int m = 0; m < 2; m++) {
      #pragma unroll
      for (int reg = 0; reg < 16; reg++) {
        float v = (n == 0 ? (m == 0 ? acc00[reg] : acc10[reg])
                          : (m == 0 ? acc01[reg] : acc11[reg])) * 2.0f;
        int i = ibase + m * 32 + (reg & 3) + 8 * (reg >> 2);
        if (i == jp) pos[j] = v;            // positive (unique writer; jp != j)
        if (i == j) v = -1.0e30f;           // diag mask
        mx = fmaxf(mx, v);
      }
    }
    float sm = 0.f;
    #pragma unroll
    for (int m = 0; m < 2; m++) {
      #pragma unroll
      for (int reg = 0; reg < 16; reg++) {
        float v = (n == 0 ? (m == 0 ? acc00[reg] : acc10[reg])
                          : (m == 0 ? acc01[reg] : acc11[reg])) * 2.0f;
        int i = ibase + m * 32 + (reg & 3) + 8 * (reg >> 2);
        if (i == j) v = -1.0e30f;
        sm += __expf(v - mx);
      }
    }
    // merge the hi pair (each lane scanned only 32 of the 64 rows)
    float mo = __shfl_xor(mx, 32);
    float so = __shfl_xor(sm, 32);
    float M = fmaxf(mx, mo);
    sm = sm * __expf(mx - M) + so * __expf(mo - M);
    if (hi == 0) lsep[(size_t)j * 64 + mslot] = make_float2(M, sm);
  }
}

// ---------------- kernel 5: per-row logsumexp merge ----------------
__global__ void k_lse(const float2* __restrict__ lsep, float* __restrict__ lse) {
  int row = (int)((blockIdx.x * blockDim.x + threadIdx.x) >> 6);
  int lane = threadIdx.x & 63;
  float2 p = lsep[(size_t)row * 64 + lane];
  float m = p.x, s = p.y;
  #pragma unroll
  for (int off = 1; off < 64; off <<= 1) {
    float mo = __shfl_xor(m, off), so = __shfl_xor(s, off);
    float M = fmaxf(m, mo);
    s = s * __expf(m - M) + so * __expf(mo - M);
    m = M;
  }
  if (lane == 0) lse[row] = m + __logf(s);
}

// ---------------- kernel 6: final scalar ----------------
__global__ void k_final(const float* __restrict__ lse, const float* __restrict__ pos,
                        float* __restrict__ out) {
  __shared__ float red[4];
  int tid = threadIdx.x;
  float a = 0.f;
  for (int i = tid; i < NFEAT; i += 256) a += lse[i] - pos[i];
  #pragma unroll
  for (int off = 32; off >= 1; off >>= 1) a += __shfl_xor(a, off);
  if ((tid & 63) == 0) red[tid >> 6] = a;
  __syncthreads();
  if (tid == 0) out[0] = (red[0] + red[1] + red[2] + red[3]) / (float)NFEAT;
}

extern "C" void kernel_launch(void* const* d_in, const int* in_sizes, int n_in,
                              void* d_out, int out_size, void* d_ws, size_t ws_size,
                              hipStream_t stream) {
  const float* zi    = (const float*)d_in[0];
  const float* zj    = (const float*)d_in[1];
  const float* queue = (const float*)d_in[2];
  float* out = (float*)d_out;
  char* ws = (char*)d_ws;

  // ws layout (bytes):
  u8*     queue8T = (u8*)(ws + 0);               // 32768*512   = 16777216
  u8*     feat8T  = (u8*)(ws + 16777216);        // 4096*512    = 2097152
  u8*     nn8T    = (u8*)(ws + 18874368);        // 4096*512    = 2097152
  u64*    part    = (u64*)(ws + 20971520);       // 4096*512*8  = 16777216
  float2* lsep    = (float2*)(ws + 37748736);    // 4096*64*8   = 2097152
  float*  pos     = (float*)(ws + 39845888);     // 4096*4      = 16384
  float*  lse     = (float*)(ws + 39862272);     // 4096*4      = 16384
  // total = 39878656 bytes (~38 MB)

  k_norm<<<9216, 256, 0, stream>>>(zi, zj, queue, feat8T, queue8T);
  k_argmax_gemm8<<<4096, 256, 0, stream>>>(feat8T, queue8T, part);
  k_reduce_gather<<<1024, 256, 0, stream>>>(part, queue8T, nn8T);
  k_sim_gemm8<<<1024, 256, 0, stream>>>(feat8T, nn8T, lsep, pos);
  k_lse<<<1024, 256, 0, stream>>>(lsep, lse);
  k_final<<<1, 256, 0, stream>>>(lse, pos, out);
}

// Round 24
// 108.113 us; speedup vs baseline: 1.0724x; 1.0724x over previous
//
#include <hip/hip_runtime.h>
#include <cstdint>

#define NFEAT 4096
#define NHALF 2048
#define DDIM  512
#define QROWS 32768

typedef unsigned short u16;
typedef unsigned char  u8;
typedef unsigned int   u32;
typedef unsigned long long u64;

typedef float  f32x16_t __attribute__((ext_vector_type(16)));
typedef int    i32x4_t  __attribute__((ext_vector_type(4)));
typedef int    i32x8_t  __attribute__((ext_vector_type(8)));

typedef const __attribute__((address_space(1))) void* gas_ptr;
typedef __attribute__((address_space(3))) void* las_ptr;

// monotonic unsigned encoding of float (no NaN/Inf expected)
__device__ __forceinline__ u32 fkey(float f) {
  u32 u = __float_as_uint(f);
  return (u & 0x80000000u) ? ~u : (u | 0x80000000u);
}

// ---------------- kernel 1: l2-normalize rows -> TILED fp8(e4m3) --------------
// fp8 buffers stored PRE-TILED in the GEMM's fragment order: addr(row,k) =
// (row>>5)*16384 + (k>>6)*2048 + ((k>>5)&1)*1024 + ((k>>4)&1)*512 +
// (row&31)*16 + (k&15).  (verified R11/R12, absmax 0.0)
__global__ void k_norm(const float* __restrict__ zi, const float* __restrict__ zj,
                       const float* __restrict__ queue,
                       u8* __restrict__ feat8T, u8* __restrict__ queue8T) {
  int gw = (int)((blockIdx.x * blockDim.x + threadIdx.x) >> 6);
  int lane = threadIdx.x & 63;
  const float* src; u8* dstT; int r31;
  if (gw < NFEAT) {
    src = (gw < NHALF) ? (zi + (size_t)gw * DDIM) : (zj + (size_t)(gw - NHALF) * DDIM);
    dstT = feat8T + (size_t)(gw >> 5) * 16384; r31 = gw & 31;
  } else {
    int r = gw - NFEAT;
    src = queue + (size_t)r * DDIM;
    dstT = queue8T + (size_t)(r >> 5) * 16384; r31 = r & 31;
  }
  float4 v0 = reinterpret_cast<const float4*>(src)[lane * 2];
  float4 v1 = reinterpret_cast<const float4*>(src)[lane * 2 + 1];
  float ss = v0.x*v0.x + v0.y*v0.y + v0.z*v0.z + v0.w*v0.w
           + v1.x*v1.x + v1.y*v1.y + v1.z*v1.z + v1.w*v1.w;
  #pragma unroll
  for (int off = 32; off >= 1; off >>= 1) ss += __shfl_xor(ss, off);
  float inv = 1.0f / fmaxf(sqrtf(ss), 1e-12f);
  float n0 = v0.x*inv, n1 = v0.y*inv, n2 = v0.z*inv, n3 = v0.w*inv;
  float n4 = v1.x*inv, n5 = v1.y*inv, n6 = v1.z*inv, n7 = v1.w*inv;
  u32 p01, p23, p45, p67;
  asm("v_cvt_pk_fp8_f32 %0, %1, %2" : "=v"(p01) : "v"(n0), "v"(n1));
  asm("v_cvt_pk_fp8_f32 %0, %1, %2" : "=v"(p23) : "v"(n2), "v"(n3));
  asm("v_cvt_pk_fp8_f32 %0, %1, %2" : "=v"(p45) : "v"(n4), "v"(n5));
  asm("v_cvt_pk_fp8_f32 %0, %1, %2" : "=v"(p67) : "v"(n6), "v"(n7));
  uint2 w8;
  w8.x = (p01 & 0xFFFFu) | (p23 << 16);
  w8.y = (p45 & 0xFFFFu) | (p67 << 16);
  size_t toff = (size_t)(lane >> 3) * 2048 + ((lane >> 2) & 1) * 1024
              + ((lane >> 1) & 1) * 512 + r31 * 16 + (lane & 1) * 8;
  *reinterpret_cast<uint2*>(dstT + toff) = w8;
}

#define SB0() __builtin_amdgcn_sched_barrier(0)
#define LGKM0_SB() do { asm volatile("s_waitcnt lgkmcnt(0)" ::: "memory"); SB0(); } while (0)
#define LGKM4_SB() do { asm volatile("s_waitcnt lgkmcnt(4)" ::: "memory"); SB0(); } while (0)
#define VMCNT6() asm volatile("s_waitcnt vmcnt(6)" ::: "memory")
#define VMCNT4() asm volatile("s_waitcnt vmcnt(4)" ::: "memory")
#define VMCNT0() asm volatile("s_waitcnt vmcnt(0)" ::: "memory")
#define SBAR() __builtin_amdgcn_s_barrier()
#define RD(dst, base, off) asm volatile("ds_read_b128 %0, %1 offset:" off \
                                        : "=v"(dst) : "v"(base))
#define MFMA8(ACC, AV, BV) \
  ACC = __builtin_amdgcn_mfma_scale_f32_32x32x64_f8f6f4(AV, BV, ACC, 0, 0, 0, \
        0x7F7F7F7F, 0, 0x7F7F7F7F)

// ---------------- kernel 2: WIDE fp8 GEMM queue @ feat^T + fused col-argmax ---
// R24 = R22 (best verified): wide 128Mx256N, 4 waves 2Mx2N, wave 64x128,
// ring-3 LDS 72KB, counted vmcnt(6), INTRA-TILE READ/MFMA OVERLAP: all 12
// ds_reads issued, lgkmcnt(4) confirms the first 8 (A + B0/B1) while B2/B3
// stay in flight and drain under the first 4-MFMA burst; lgkmcnt(0) before
// the second burst. Ledger: prologue stage(0),stage(1) -> vmcnt(6); iter t
// stage(t+2) -> buf (t+2)%3 = (t-1)%3 (readers of t-1 lgkm-confirmed before
// t-1's ending barrier -> WAR safe); boundary t<=5 vmcnt(6), t=6 vmcnt(0),
// t=7 none. Epilogue = verified R12 in-register col-argmax x 4 n-groups.
__global__ __launch_bounds__(256, 2) void k_argmax_gemm8(
    const u8* __restrict__ feat8T, const u8* __restrict__ queue8T,
    u64* __restrict__ part) {
  __shared__ u8 lds[73728];
  const int tid = threadIdx.x;
  const int w = tid >> 6, lane = tid & 63;
  const int wr = w >> 1, wc = w & 1;
  const int l31 = lane & 31, hi = lane >> 5;
  const int bid = (int)blockIdx.x;
  const int wg = (bid & 7) * 512 + (bid >> 3);   // bijective XCD swizzle (4096 = 8x512)
  const int mt = wg >> 4, ft = wg & 15;          // ft fastest: queue slice L2-resident
  const int brow = mt * 128, bcol = ft * 256;

  const u8* pA = queue8T + (size_t)(brow >> 5) * 16384 + (tid >> 7) * 16384 + (tid & 127) * 16;
  const u8* pB = feat8T  + (size_t)(bcol >> 5) * 16384 + (tid >> 7) * 16384 + (tid & 127) * 16;
  const u32 dA = (u32)(size_t)(las_ptr)&lds[tid * 16];
  const u32 dB = dA + 8192;

  // read bases: A rows (wave wr), B cols (wave wc = 128-col half)
  const u32 aAd = (u32)(size_t)(las_ptr)&lds[wr * 4096 + hi * 1024 + l31 * 16];
  const u32 bAd = (u32)(size_t)(las_ptr)&lds[8192 + wc * 8192 + hi * 1024 + l31 * 16];

  f32x16_t acc00 = {}, acc01 = {}, acc02 = {}, acc03 = {};
  f32x16_t acc10 = {}, acc11 = {}, acc12 = {}, acc13 = {};

  auto stage = [&](int b, int t) {
    const u32 base = (u32)(b * 24576);
    __builtin_amdgcn_global_load_lds((gas_ptr)(pA + t * 2048),         (las_ptr)(size_t)(dA + base), 16, 0, 0);
    __builtin_amdgcn_global_load_lds((gas_ptr)(pA + 32768 + t * 2048), (las_ptr)(size_t)(dA + base + 4096), 16, 0, 0);
    __builtin_amdgcn_global_load_lds((gas_ptr)(pB + t * 2048),         (las_ptr)(size_t)(dB + base), 16, 0, 0);
    __builtin_amdgcn_global_load_lds((gas_ptr)(pB + 32768 + t * 2048), (las_ptr)(size_t)(dB + base + 4096), 16, 0, 0);
    __builtin_amdgcn_global_load_lds((gas_ptr)(pB + 65536 + t * 2048), (las_ptr)(size_t)(dB + base + 8192), 16, 0, 0);
    __builtin_amdgcn_global_load_lds((gas_ptr)(pB + 98304 + t * 2048), (las_ptr)(size_t)(dB + base + 12288), 16, 0, 0);
  };

  stage(0, 0); stage(1, 1);
  VMCNT6();
  SBAR();

  #pragma unroll
  for (int t = 0; t < 8; t++) {
    if (t <= 5) stage((t + 2) % 3, t + 2);
    const u32 bb = (u32)((t % 3) * 24576);
    const u32 xa = aAd + bb, xb = bAd + bb;
    i32x4_t r0, r1, r2, r3, s0, s1, s2, s3, s4, s5, s6, s7;
    // group 1: A (4) + B0/B1 (4)
    RD(r0, xa, "0");    RD(r1, xa, "512");
    RD(r2, xa, "2048"); RD(r3, xa, "2560");
    RD(s0, xb, "0");    RD(s1, xb, "512");
    RD(s2, xb, "2048"); RD(s3, xb, "2560");
    // group 2: B2/B3 (4) -- drain under the first MFMA burst
    RD(s4, xb, "4096"); RD(s5, xb, "4608");
    RD(s6, xb, "6144"); RD(s7, xb, "6656");
    LGKM4_SB();                    // first 8 complete; last 4 in flight
    i32x8_t A0 = __builtin_shufflevector(r0, r1, 0, 1, 2, 3, 4, 5, 6, 7);
    i32x8_t A1 = __builtin_shufflevector(r2, r3, 0, 1, 2, 3, 4, 5, 6, 7);
    i32x8_t B0 = __builtin_shufflevector(s0, s1, 0, 1, 2, 3, 4, 5, 6, 7);
    i32x8_t B1 = __builtin_shufflevector(s2, s3, 0, 1, 2, 3, 4, 5, 6, 7);
    __builtin_amdgcn_s_setprio(1);
    MFMA8(acc00, A0, B0); MFMA8(acc01, A0, B1);
    MFMA8(acc10, A1, B0); MFMA8(acc11, A1, B1);
    __builtin_amdgcn_s_setprio(0);
    LGKM0_SB();                    // B2/B3 complete
    i32x8_t B2 = __builtin_shufflevector(s4, s5, 0, 1, 2, 3, 4, 5, 6, 7);
    i32x8_t B3 = __builtin_shufflevector(s6, s7, 0, 1, 2, 3, 4, 5, 6, 7);
    __builtin_amdgcn_s_setprio(1);
    MFMA8(acc02, A0, B2); MFMA8(acc03, A0, B3);
    MFMA8(acc12, A1, B2); MFMA8(acc13, A1, B3);
    __builtin_amdgcn_s_setprio(0);
    if (t < 7) {
      if (t <= 5) VMCNT6(); else VMCNT0();
      SBAR();
    }
  }

  // epilogue: per-feature (column = lane pair) argmax over wave's 64 queue rows.
  // C/D 32x32: col = lane&31, row = (reg&3) + 8*(reg>>2) + 4*hi (+m*32).
  const int mslot = mt * 2 + wr;
#define AMAX_N(ACC0, ACC1, NOFF) do { \
    float bv = -3.0e38f; int br = 0; \
    _Pragma("unroll") \
    for (int reg = 0; reg < 16; reg++) { \
      float v = ACC0[reg]; int lr = (reg & 3) + 8 * (reg >> 2); \
      if (v > bv) { bv = v; br = lr; } } \
    _Pragma("unroll") \
    for (int reg = 0; reg < 16; reg++) { \
      float v = ACC1[reg]; int lr = 32 + (reg & 3) + 8 * (reg >> 2); \
      if (v > bv) { bv = v; br = lr; } } \
    u32 q = (u32)(brow + wr * 64 + br + 4 * hi); \
    u64 key = ((u64)fkey(bv) << 32) | (u64)(0xFFFFFFFFu - q); \
    u64 o = __shfl_xor(key, 32); \
    key = key > o ? key : o; \
    int j = bcol + wc * 128 + NOFF + l31; \
    if (hi == 0) part[(size_t)j * 512 + mslot] = key; \
  } while (0)
  AMAX_N(acc00, acc10, 0);
  AMAX_N(acc01, acc11, 32);
  AMAX_N(acc02, acc12, 64);
  AMAX_N(acc03, acc13, 96);
#undef AMAX_N
}

// ---------------- kernel 3: reduce argmax partials + FUSED row gather ---------
__global__ void k_reduce_gather(const u64* __restrict__ part,
                                const u8* __restrict__ queue8T,
                                u8* __restrict__ nn8T) {
  int row = (int)((blockIdx.x * blockDim.x + threadIdx.x) >> 6);
  int lane = threadIdx.x & 63;
  const u64* p = part + (size_t)row * 512;
  u64 best = 0;
  #pragma unroll
  for (int i = 0; i < 8; i++) { u64 v = p[lane * 8 + i]; best = best > v ? best : v; }
  #pragma unroll
  for (int off = 1; off < 64; off <<= 1) { u64 o = __shfl_xor(best, off); best = best > o ? best : o; }
  int g = (int)(0xFFFFFFFFu - (u32)(best & 0xFFFFFFFFu));
  if (lane < 32) {
    const uint4 v = *reinterpret_cast<const uint4*>(
        queue8T + (size_t)(g >> 5) * 16384 + lane * 512 + (g & 31) * 16);
    *reinterpret_cast<uint4*>(
        nn8T + (size_t)(row >> 5) * 16384 + lane * 512 + (row & 31) * 16) = v;
  }
}

// ---------------- R12 tile engine (narrow, verified) for k_sim_gemm8 ----------
#define FP8_TILE(XA, XB) do { \
    i32x4_t a00, a01, a10, a11, b00, b01, b10, b11; \
    RD(a00, XA, "0"); RD(a01, XA, "512"); \
    RD(a10, XA, "2048"); RD(a11, XA, "2560"); \
    RD(b00, XB, "0"); RD(b01, XB, "512"); \
    RD(b10, XB, "2048"); RD(b11, XB, "2560"); \
    LGKM0_SB(); \
    i32x8_t A0 = __builtin_shufflevector(a00, a01, 0, 1, 2, 3, 4, 5, 6, 7); \
    i32x8_t A1 = __builtin_shufflevector(a10, a11, 0, 1, 2, 3, 4, 5, 6, 7); \
    i32x8_t B0 = __builtin_shufflevector(b00, b01, 0, 1, 2, 3, 4, 5, 6, 7); \
    i32x8_t B1 = __builtin_shufflevector(b10, b11, 0, 1, 2, 3, 4, 5, 6, 7); \
    __builtin_amdgcn_s_setprio(1); \
    MFMA8(acc00, A0, B0); \
    MFMA8(acc01, A0, B1); \
    MFMA8(acc10, A1, B0); \
    MFMA8(acc11, A1, B1); \
    __builtin_amdgcn_s_setprio(0); \
  } while (0)

#define FP8_MAIN_LOOP() do { \
  stage(0, 0); stage(1, 1); \
  VMCNT4(); \
  SBAR(); \
  _Pragma("unroll") \
  for (int t = 0; t < 8; t++) { \
    if (t <= 5) stage((t + 2) % 3, t + 2); \
    const u32 bb = (u32)((t % 3) * 16384); \
    FP8_TILE(aAd + bb, bAd + bb); \
    if (t < 7) { \
      if (t <= 5) VMCNT4(); else VMCNT0(); \
      SBAR(); \
    } \
  } } while (0)

// ---------------- kernel 4: fp8 GEMM feat @ nn^T + fused col-lse + positives --
// (verified R16: contiguous nn8T staging, lane-pair lse + hi merge)
__global__ __launch_bounds__(256, 2) void k_sim_gemm8(
    const u8* __restrict__ feat8T, const u8* __restrict__ nn8T,
    float2* __restrict__ lsep, float* __restrict__ pos) {
  __shared__ u8 lds[49152];
  const int tid = threadIdx.x;
  const int w = tid >> 6, lane = tid & 63;
  const int wr = w >> 1, wc = w & 1;
  const int l31 = lane & 31, hi = lane >> 5;
  const int bid = (int)blockIdx.x;
  const int wg = (bid & 7) * 128 + (bid >> 3);   // bijective XCD swizzle (1024 = 8x128)
  const int mt = wg >> 5, nt = wg & 31;
  const int mtb = mt * 128, ntb = nt * 128;

  const u8* pA = feat8T + (size_t)(mtb >> 5) * 16384 + (tid >> 7) * 16384 + (tid & 127) * 16;
  const u8* pB = nn8T   + (size_t)(ntb >> 5) * 16384 + (tid >> 7) * 16384 + (tid & 127) * 16;
  const u32 dA = (u32)(size_t)(las_ptr)&lds[tid * 16];
  const u32 dB = dA + 8192;

  const u32 aAd = (u32)(size_t)(las_ptr)&lds[wr * 4096 + hi * 1024 + l31 * 16];
  const u32 bAd = (u32)(size_t)(las_ptr)&lds[8192 + wc * 4096 + hi * 1024 + l31 * 16];

  f32x16_t acc00 = {}, acc01 = {}, acc10 = {}, acc11 = {};

  auto stage = [&](int b, int t) {
    const u32 base = (u32)(b * 16384);
    __builtin_amdgcn_global_load_lds((gas_ptr)(pA + t * 2048),         (las_ptr)(size_t)(dA + base), 16, 0, 0);
    __builtin_amdgcn_global_load_lds((gas_ptr)(pA + 32768 + t * 2048), (las_ptr)(size_t)(dA + base + 4096), 16, 0, 0);
    __builtin_amdgcn_global_load_lds((gas_ptr)(pB + t * 2048),         (las_ptr)(size_t)(dB + base), 16, 0, 0);
    __builtin_amdgcn_global_load_lds((gas_ptr)(pB + 32768 + t * 2048), (las_ptr)(size_t)(dB + base + 4096), 16, 0, 0);
  };

  FP8_MAIN_LOOP();

  // epilogue: per-column (lane pair = nn row j) lse over 64 feat rows,
  // scale by 1/T=2, diag mask, positive capture, hi-pair online-softmax merge.
  const int mslot = mt * 2 + wr;
  const int ibase = mtb + wr * 64 + 4 * hi;
  #pragma unroll
  for (int n = 0; n < 2; n++) {
    const int j = ntb + wc * 64 + n * 32 + l31;
    const int jp = j ^ NHALF;
    float mx = -3.0e38f;
    #pragma unroll
    for (int m = 0; m < 2; m++) {
      #pragma unroll
      for (int reg = 0; reg < 16; reg++) {
        float v = (n == 0 ? (m == 0 ? acc00[reg] : acc10[reg])
                          : (m == 0 ? acc01[reg] : acc11[reg])) * 2.0f;
        int i = ibase + m * 32 + (reg & 3) + 8 * (reg >> 2);
        if (i == jp) pos[j] = v;            // positive (unique writer; jp != j)
        if (i == j) v = -1.0e30f;           // diag mask
        mx = fmaxf(mx, v);
      }
    }
    float sm = 0.f;
    #pragma unroll
    for (int m = 0; m < 2; m++) {
      #pragma unroll
      for (int reg = 0; reg < 16; reg++) {
        float v = (n == 0 ? (m == 0 ? acc00[reg] : acc10[reg])
                          : (m == 0 ? acc01[reg] : acc11[reg])) * 2.0f;
        int i = ibase + m * 32 + (reg & 3) + 8 * (reg >> 2);
        if (i == j) v = -1.0e30f;
        sm += __expf(v - mx);
      }
    }
    // merge the hi pair (each lane scanned only 32 of the 64 rows)
    float mo = __shfl_xor(mx, 32);
    float so = __shfl_xor(sm, 32);
    float M = fmaxf(mx, mo);
    sm = sm * __expf(mx - M) + so * __expf(mo - M);
    if (hi == 0) lsep[(size_t)j * 64 + mslot] = make_float2(M, sm);
  }
}

// ---------------- kernel 5: per-row logsumexp merge ----------------
__global__ void k_lse(const float2* __restrict__ lsep, float* __restrict__ lse) {
  int row = (int)((blockIdx.x * blockDim.x + threadIdx.x) >> 6);
  int lane = threadIdx.x & 63;
  float2 p = lsep[(size_t)row * 64 + lane];
  float m = p.x, s = p.y;
  #pragma unroll
  for (int off = 1; off < 64; off <<= 1) {
    float mo = __shfl_xor(m, off), so = __shfl_xor(s, off);
    float M = fmaxf(m, mo);
    s = s * __expf(m - M) + so * __expf(mo - M);
    m = M;
  }
  if (lane == 0) lse[row] = m + __logf(s);
}

// ---------------- kernel 6: final scalar ----------------
__global__ void k_final(const float* __restrict__ lse, const float* __restrict__ pos,
                        float* __restrict__ out) {
  __shared__ float red[4];
  int tid = threadIdx.x;
  float a = 0.f;
  for (int i = tid; i < NFEAT; i += 256) a += lse[i] - pos[i];
  #pragma unroll
  for (int off = 32; off >= 1; off >>= 1) a += __shfl_xor(a, off);
  if ((tid & 63) == 0) red[tid >> 6] = a;
  __syncthreads();
  if (tid == 0) out[0] = (red[0] + red[1] + red[2] + red[3]) / (float)NFEAT;
}

extern "C" void kernel_launch(void* const* d_in, const int* in_sizes, int n_in,
                              void* d_out, int out_size, void* d_ws, size_t ws_size,
                              hipStream_t stream) {
  const float* zi    = (const float*)d_in[0];
  const float* zj    = (const float*)d_in[1];
  const float* queue = (const float*)d_in[2];
  float* out = (float*)d_out;
  char* ws = (char*)d_ws;

  // ws layout (bytes):
  u8*     queue8T = (u8*)(ws + 0);               // 32768*512   = 16777216
  u8*     feat8T  = (u8*)(ws + 16777216);        // 4096*512    = 2097152
  u8*     nn8T    = (u8*)(ws + 18874368);        // 4096*512    = 2097152
  u64*    part    = (u64*)(ws + 20971520);       // 4096*512*8  = 16777216
  float2* lsep    = (float2*)(ws + 37748736);    // 4096*64*8   = 2097152
  float*  pos     = (float*)(ws + 39845888);     // 4096*4      = 16384
  float*  lse     = (float*)(ws + 39862272);     // 4096*4      = 16384
  // total = 39878656 bytes (~38 MB)

  k_norm<<<9216, 256, 0, stream>>>(zi, zj, queue, feat8T, queue8T);
  k_argmax_gemm8<<<4096, 256, 0, stream>>>(feat8T, queue8T, part);
  k_reduce_gather<<<1024, 256, 0, stream>>>(part, queue8T, nn8T);
  k_sim_gemm8<<<1024, 256, 0, stream>>>(feat8T, nn8T, lsep, pos);
  k_lse<<<1024, 256, 0, stream>>>(lsep, lse);
  k_final<<<1, 256, 0, stream>>>(lse, pos, out);
}